// Round 10
// baseline (31.001 us; speedup 1.0000x reference)
//
#include <hip/hip_runtime.h>
#include <hip/hip_fp16.h>
#include <math.h>

#define NQ 8

// ---------- compile-time GF(2) circuit algebra (validated: rounds 2-9, absmax=0 in f32) ----------
// wire w <-> amp-index bit (7-w). CNOT(c,t): bit_t ^= bit_c.
__host__ __device__ constexpr int cnot_step(int i, int c, int t) {
    return ((i >> (7 - c)) & 1) ? (i ^ (1 << (7 - t))) : i;
}
__host__ __device__ constexpr int sigma_fwd(int i, int r) {
    for (int q = 0; q < 8; ++q) i = cnot_step(i, q, (q + r) & 7);
    return i;
}
__host__ __device__ constexpr int sigma_inv(int i, int r) {
    for (int q = 7; q >= 0; --q) i = cnot_step(i, q, (q + r) & 7);
    return i;
}
__host__ __device__ constexpr int pairmask(int q) { return sigma_inv(1 << (7 - q), 1); }
__host__ __device__ constexpr int rolemask(int q) {
    int m = 0;
    for (int j = 0; j < 8; ++j)
        if ((sigma_fwd(1 << j, 1) >> (7 - q)) & 1) m |= 1 << j;
    return m;
}
__host__ __device__ constexpr int colmask2(int b) {
    return sigma_fwd(sigma_fwd(1 << b, 1), 2);
}

// ---------- amp-index bit assignment (8 samples/wave, 32 amps/lane, SoA f16x2) ----------
// b7=slot, b6=k3, b5=hl0, b4=hl1, b3=hl2, b2=k2, b1=k1, b0=k0
__host__ __device__ constexpr int amp_index(int slot, int k, int hl) {
    return (slot << 7) | (((k >> 3) & 1) << 6) | ((hl & 1) << 5) | (((hl >> 1) & 1) << 4)
         | (((hl >> 2) & 1) << 3) | (((k >> 2) & 1) << 2) | (((k >> 1) & 1) << 1) | (k & 1);
}
__host__ __device__ constexpr int mask_slot(int M) { return (M >> 7) & 1; }
__host__ __device__ constexpr int mask_k(int M) {
    return (((M >> 6) & 1) << 3) | (((M >> 2) & 1) << 2) | (((M >> 1) & 1) << 1) | (M & 1);
}
__host__ __device__ constexpr int mask_l(int M) {
    return ((M >> 5) & 1) | (((M >> 4) & 1) << 1) | (((M >> 3) & 1) << 2);
}

typedef _Float16 h2v __attribute__((ext_vector_type(2)));

__device__ __forceinline__ __half2 bc_h2(uint32_t u) { return __builtin_bit_cast(__half2, u); }
__device__ __forceinline__ uint32_t bc_u32(__half2 h) { return __builtin_bit_cast(uint32_t, h); }
__device__ __forceinline__ h2v bc_hv(__half2 h) { return __builtin_bit_cast(h2v, h); }
__device__ __forceinline__ uint32_t rot16(uint32_t u) { return (u >> 16) | (u << 16); }

// lane' = lane ^ XM via BitMode ds_swizzle (stays within 8-lane sample group for XM<8)
template<int XM>
__device__ __forceinline__ uint32_t swzu(uint32_t v) {
    return (uint32_t)__builtin_amdgcn_ds_swizzle((int)v, (XM << 10) | 0x1F);
}
// lane' = lane ^ {1,3} via quad-perm DPP (VALU, no LDS pipe)
template<int CTRL>
__device__ __forceinline__ uint32_t dppx(uint32_t v) {
    return (uint32_t)__builtin_amdgcn_update_dpp(0, (int)v, CTRL, 0xF, 0xF, true);
}
// reduction add with fused DPP permute: xor1=0xB1, xor2=0x4E, lane^7=row_half_mirror=0x141
template<int CTRL>
__device__ __forceinline__ float dppaddf(float v) {
    const uint32_t p = (uint32_t)__builtin_amdgcn_update_dpp(
        0, (int)__builtin_bit_cast(uint32_t, v), CTRL, 0xF, 0xF, true);
    return v + __builtin_bit_cast(float, p);
}

__device__ __forceinline__ void cmul(float& zr, float& zi,
                                     float xr, float xi, float yr, float yi) {
    const float tr = xr * yr - xi * yi;
    const float ti = xr * yi + xi * yr;
    zr = tr; zi = ti;
}

// packed complex pair {slot0, slot1} and broadcast complex coefficient
struct H2C { __half2 re, im; };
struct YB  { __half2 re, im, imn; };
__device__ __forceinline__ YB mkyb(float r, float i) {
    YB y;
    y.re  = __floats2half2_rn(r, r);
    y.im  = __floats2half2_rn(i, i);
    y.imn = bc_h2(bc_u32(y.im) ^ 0x80008000u);
    return y;
}
__device__ __forceinline__ H2C h2c_mul(H2C x, YB y) {
    H2C z;
    z.re = __hfma2(x.im, y.imn, __hmul2(x.re, y.re));
    z.im = __hfma2(x.im, y.re,  __hmul2(x.re, y.im));
    return z;
}

// ---------- generalized layer-2 gate, SoA packed f16, 32 amps/lane ----------
template<int Q>
__device__ __forceinline__ void gateQ(__half2 re[16], __half2 im[16], int hl,
                                      const uint32_t* __restrict__ cw)
{
    constexpr int M  = pairmask(Q);
    constexpr int RM = rolemask(Q);
    constexpr int mk = mask_k(M);
    constexpr int ml = mask_l(M);
    constexpr int ms = mask_slot(M);
    constexpr int rk = mask_k(RM);
    constexpr int rl = mask_l(RM);

    const uint4    c4v = *(const uint4*)(cw + Q * 8); // {WA, WB0, WC0(-C), WD}
    const uint32_t WDn = cw[Q * 8 + 4];               // {-D,-D}

    const uint32_t pm = (uint32_t)(__popc(hl & rl) & 1) * 0x80008000u;
    const uint32_t Bp = c4v.y ^ pm, Bn = Bp ^ 0x80008000u;
    const uint32_t Cp = c4v.z ^ pm, Cn = Cp ^ 0x80008000u;
    const __half2  Aw = bc_h2(c4v.x);
    const __half2  Dw = bc_h2(c4v.w);
    const __half2  Dn = bc_h2(WDn);

    auto prep = [](uint32_t v) -> uint32_t {
        if constexpr (ms) v = rot16(v);
        if constexpr (ml == 1) v = dppx<0xB1>(v);
        else if constexpr (ml == 3) v = dppx<0x1B>(v);
        else if constexpr (ml != 0) v = swzu<ml>(v);
        return v;
    };
    auto upd = [&](int k, uint32_t pr, uint32_t pi) {
        const bool par = (__popc(k & rk) & 1) != 0;   // compile-time after unroll
        const __half2 B1 = bc_h2(par ? Bn : Bp);
        const __half2 B2 = bc_h2(par ? Bp : Bn);
        const __half2 Cc = bc_h2(par ? Cn : Cp);
        __half2 nr = __hmul2(Aw, re[k]);
        nr = __hfma2(B1, im[k], nr);
        nr = __hfma2(Cc, bc_h2(pr), nr);
        nr = __hfma2(Dw, bc_h2(pi), nr);
        __half2 ni = __hmul2(Aw, im[k]);
        ni = __hfma2(B2, re[k], ni);
        ni = __hfma2(Cc, bc_h2(pi), ni);
        ni = __hfma2(Dn, bc_h2(pr), ni);
        re[k] = nr; im[k] = ni;
    };

    if constexpr (mk == 0) {
#pragma unroll
        for (int k = 0; k < 16; ++k) {
            const uint32_t pr = prep(bc_u32(re[k]));
            const uint32_t pi = prep(bc_u32(im[k]));
            upd(k, pr, pi);
        }
    } else {
        constexpr int msb = (mk & 8) ? 8 : ((mk & 4) ? 4 : ((mk & 2) ? 2 : 1));
#pragma unroll
        for (int k = 0; k < 16; ++k) {
            if ((k & msb) != 0) continue;            // compile-time (unrolled)
            const int k2 = k ^ mk;
            const uint32_t pr_k  = prep(bc_u32(re[k2]));
            const uint32_t pi_k  = prep(bc_u32(im[k2]));
            const uint32_t pr_k2 = prep(bc_u32(re[k]));
            const uint32_t pi_k2 = prep(bc_u32(im[k]));
            upd(k,  pr_k,  pi_k);
            upd(k2, pr_k2, pi_k2);
        }
    }
}

// ---------- single fused kernel: block = 32 samples, cooperative setup ----------
__global__ __launch_bounds__(256) void vqe_fused(
    const float* __restrict__ x,       // (B,8)
    const float* __restrict__ weights, // (2,8,3)
    const float* __restrict__ fc_w,    // (8)
    const float* __restrict__ fc_b,    // (1)
    float* __restrict__ out, int B)
{
    __shared__ __align__(16) float    g0[64];        // layer-0 Rot entries (f32)
    __shared__ __align__(16) uint32_t cw[64];        // layer-1 coeff words, 8/gate
    __shared__ __align__(16) float    cols[32 * 36]; // [s][q][4]={ar,ai,br,bi}, stride 36
    __shared__ __align__(16) uint32_t wth2[8 * 20];  // [hl][k] f16x2 {w_s0,w_s1}, stride 20

    const int t = threadIdx.x;

    // --- phase A: shared trig (t<16) + packed weight table (t>=128) ---
    if (t < 8) {
        const float* w3 = weights + t * 3;
        float s, c;   __sincosf(w3[1] * 0.5f, &s, &c);
        float sa, ca; __sincosf(0.5f * (w3[0] + w3[2]), &sa, &ca);
        float sb, cb; __sincosf(0.5f * (w3[0] - w3[2]), &sb, &cb);
        float* g = g0 + t * 8;
        g[0] = c * ca;  g[1] = -c * sa;
        g[2] = -s * cb; g[3] = -s * sb;
        g[4] = s * cb;  g[5] = -s * sb;
        g[6] = c * ca;  g[7] = c * sa;
    } else if (t < 16) {
        const int q = t - 8;
        const float* w3 = weights + (NQ + q) * 3;
        float s, c;   __sincosf(w3[1] * 0.5f, &s, &c);
        float sa, ca; __sincosf(0.5f * (w3[0] + w3[2]), &sa, &ca);
        float sb, cb; __sincosf(0.5f * (w3[0] - w3[2]), &sb, &cb);
        const float A = c * ca, Bc = c * sa, C = s * cb, D = s * sb;
        const float s1 = (rolemask(q) & 0x80) ? -1.f : 1.f;   // slot-bit role sign
        uint32_t* cq = cw + q * 8;
        cq[0] = bc_u32(__floats2half2_rn(A, A));
        cq[1] = bc_u32(__floats2half2_rn(Bc, s1 * Bc));
        cq[2] = bc_u32(__floats2half2_rn(-C, -s1 * C));
        cq[3] = bc_u32(__floats2half2_rn(D, D));
        cq[4] = bc_u32(__floats2half2_rn(-D, -D));
        cq[5] = 0; cq[6] = 0; cq[7] = 0;
    } else if (t >= 128) {
        const int tt = t - 128;                // 0..127
        const int whl = tt >> 4, wk = tt & 15;
        float wsl[2];
#pragma unroll
        for (int slot = 0; slot < 2; ++slot) {
            const int s = amp_index(slot, wk, whl);
            int j = 0;
#pragma unroll
            for (int b = 0; b < 8; ++b)
                if ((s >> b) & 1) j ^= colmask2(b);
            float w = 0.f;
#pragma unroll
            for (int q = 0; q < 8; ++q)
                w += ((j >> (7 - q)) & 1) ? -fc_w[q] : fc_w[q];
            wsl[slot] = w;
        }
        wth2[whl * 20 + wk] = bc_u32(__floats2half2_rn(wsl[0], wsl[1]));
    }
    __syncthreads();

    // --- phase B: cooperative per-sample columns (1 sincos per thread, all 256) ---
    {
        const int s = t >> 3, q = t & 7;
        const int sg = blockIdx.x * 32 + s;
        if (sg < B) {
            const float xv = x[sg * NQ + q];   // addr = blockIdx*256 + t : coalesced
            float sn, cs; __sincosf(xv * 0.5f, &sn, &cs);
            const float* g = g0 + q * 8;
            float* c = cols + s * 36 + q * 4;
            c[0] = cs * g[0] + sn * g[3];   // a_r
            c[1] = cs * g[1] - sn * g[2];   // a_i
            c[2] = cs * g[4] + sn * g[7];   // b_r
            c[3] = cs * g[5] - sn * g[6];   // b_i
        }
    }
    __syncthreads();

    // --- main: 8 samples/wave, 8 lanes each, 32 amps/lane (16 re + 16 im f16x2) ---
    const int lane = t & 63;
    const int hl   = lane & 7;
    const int sidx = ((t >> 6) << 3) | ((lane >> 3) & 7);   // 0..31
    const int samp = blockIdx.x * 32 + sidx;
    if (samp >= B) return;

    const float* cb = cols + sidx * 36;

    // lane wires 2,3,4 <- hl bits 0,1,2: selected column halves, f32 chain
    const float2 e2 = *(const float2*)(cb + 2 * 4 + (hl & 1) * 2);
    const float2 e3 = *(const float2*)(cb + 3 * 4 + ((hl >> 1) & 1) * 2);
    const float2 e4 = *(const float2*)(cb + 4 * 4 + ((hl >> 2) & 1) * 2);
    float cr = e2.x, ci = e2.y;
    cmul(cr, ci, cr, ci, e3.x, e3.y);
    cmul(cr, ci, cr, ci, e4.x, e4.y);

    // full columns: wire0 (slot), wire1 (k3), wire5 (k2), wire6 (k1), wire7 (k0)
    const float4 c0 = *(const float4*)(cb + 0 * 4);
    const float4 c1 = *(const float4*)(cb + 1 * 4);
    const float4 c5 = *(const float4*)(cb + 5 * 4);
    const float4 c6 = *(const float4*)(cb + 6 * 4);
    const float4 c7 = *(const float4*)(cb + 7 * 4);

    // slot stage: S = {c*a0, c*b0}
    float w0r, w0i, w1r, w1i;
    cmul(w0r, w0i, cr, ci, c0.x, c0.y);
    cmul(w1r, w1i, cr, ci, c0.z, c0.w);
    H2C S{__floats2half2_rn(w0r, w1r), __floats2half2_rn(w0i, w1i)};

    // doubling tree over reg qubits k3(wire1), k2(wire5), k1(wire6), k0(wire7)
    const YB y1a = mkyb(c1.x, c1.y), y1b = mkyb(c1.z, c1.w);
    const YB y5a = mkyb(c5.x, c5.y), y5b = mkyb(c5.z, c5.w);
    const YB y6a = mkyb(c6.x, c6.y), y6b = mkyb(c6.z, c6.w);
    const YB y7a = mkyb(c7.x, c7.y), y7b = mkyb(c7.z, c7.w);

    const H2C A0 = h2c_mul(S, y1a);
    const H2C A1 = h2c_mul(S, y1b);
    H2C Bv[4];
    Bv[0] = h2c_mul(A0, y5a); Bv[1] = h2c_mul(A0, y5b);
    Bv[2] = h2c_mul(A1, y5a); Bv[3] = h2c_mul(A1, y5b);
    H2C Cv[8];
#pragma unroll
    for (int j = 0; j < 4; ++j) {
        Cv[j * 2 + 0] = h2c_mul(Bv[j], y6a);
        Cv[j * 2 + 1] = h2c_mul(Bv[j], y6b);
    }
    __half2 re[16], im[16];
#pragma unroll
    for (int j = 0; j < 8; ++j) {
        const H2C z0 = h2c_mul(Cv[j], y7a);
        const H2C z1 = h2c_mul(Cv[j], y7b);
        re[j * 2 + 0] = z0.re; im[j * 2 + 0] = z0.im;
        re[j * 2 + 1] = z1.re; im[j * 2 + 1] = z1.im;
    }

    // layer-2 Rot gates (CNOT layers folded away; algebra validated rounds 2-9)
    gateQ<0>(re, im, hl, cw);
    gateQ<1>(re, im, hl, cw);
    gateQ<2>(re, im, hl, cw);
    gateQ<3>(re, im, hl, cw);
    gateQ<4>(re, im, hl, cw);
    gateQ<5>(re, im, hl, cw);
    gateQ<6>(re, im, hl, cw);
    gateQ<7>(re, im, hl, cw);

    // readout: acc += w*(re^2 + im^2) via packed mul + v_dot2_f32_f16
    const uint32_t* wrow = wth2 + hl * 20;
    const uint4 wa = *(const uint4*)(wrow + 0);
    const uint4 wb = *(const uint4*)(wrow + 4);
    const uint4 wc = *(const uint4*)(wrow + 8);
    const uint4 wd = *(const uint4*)(wrow + 12);
    const uint32_t wkw[16] = {wa.x, wa.y, wa.z, wa.w, wb.x, wb.y, wb.z, wb.w,
                              wc.x, wc.y, wc.z, wc.w, wd.x, wd.y, wd.z, wd.w};

    float acc = 0.f;
#pragma unroll
    for (int k = 0; k < 16; ++k) {
        const __half2 W = bc_h2(wkw[k]);
        const __half2 tr_ = __hmul2(re[k], W);
        const __half2 ti_ = __hmul2(im[k], W);
#if defined(__has_builtin) && __has_builtin(__builtin_amdgcn_fdot2)
        acc = __builtin_amdgcn_fdot2(bc_hv(tr_), bc_hv(re[k]), acc, false);
        acc = __builtin_amdgcn_fdot2(bc_hv(ti_), bc_hv(im[k]), acc, false);
#else
        acc += __low2float(tr_) * __low2float(re[k]) + __high2float(tr_) * __high2float(re[k]);
        acc += __low2float(ti_) * __low2float(im[k]) + __high2float(ti_) * __high2float(im[k]);
#endif
    }
    // 8-lane reduce: DPP xor1, xor2, lane^7 (row_half_mirror)
    acc = dppaddf<0xB1>(acc);
    acc = dppaddf<0x4E>(acc);
    acc = dppaddf<0x141>(acc);

    if (hl == 0) {
        const float z = acc + fc_b[0];
        out[samp] = 1.0f / (1.0f + __expf(-z));
    }
}

extern "C" void kernel_launch(void* const* d_in, const int* in_sizes, int n_in,
                              void* d_out, int out_size, void* d_ws, size_t ws_size,
                              hipStream_t stream) {
    const float* x       = (const float*)d_in[0];
    const float* weights = (const float*)d_in[1];
    const float* fc_w    = (const float*)d_in[2];
    const float* fc_b    = (const float*)d_in[3];
    float* out = (float*)d_out;
    (void)d_ws; (void)ws_size;

    const int B = in_sizes[0] / NQ;        // 32768
    const int blocks = (B + 31) / 32;      // 32 samples per 256-thread block

    // DIAGNOSTIC ROUND: launch the identical kernel twice (second launch
    // recomputes and overwrites the same outputs — deterministic, capture-safe).
    // dur_r10 ~= F + 2T vs round-9's F + T = 18.2 us resolves fixed-floor F
    // and kernel time T. See round-10 theory for the pre-committed read.
    vqe_fused<<<blocks, 256, 0, stream>>>(x, weights, fc_w, fc_b, out, B);
    vqe_fused<<<blocks, 256, 0, stream>>>(x, weights, fc_w, fc_b, out, B);
}

// Round 11
// 19.115 us; speedup vs baseline: 1.6218x; 1.6218x over previous
//
#include <hip/hip_runtime.h>
#include <hip/hip_fp16.h>
#include <math.h>

#define NQ 8

// ---------- compile-time GF(2) circuit algebra (validated: rounds 2-9, absmax=0 in f32) ----------
// wire w <-> amp-index bit (7-w). CNOT(c,t): bit_t ^= bit_c.
__host__ __device__ constexpr int cnot_step(int i, int c, int t) {
    return ((i >> (7 - c)) & 1) ? (i ^ (1 << (7 - t))) : i;
}
__host__ __device__ constexpr int sigma_fwd(int i, int r) {
    for (int q = 0; q < 8; ++q) i = cnot_step(i, q, (q + r) & 7);
    return i;
}
__host__ __device__ constexpr int sigma_inv(int i, int r) {
    for (int q = 7; q >= 0; --q) i = cnot_step(i, q, (q + r) & 7);
    return i;
}
__host__ __device__ constexpr int pairmask(int q) { return sigma_inv(1 << (7 - q), 1); }
__host__ __device__ constexpr int rolemask(int q) {
    int m = 0;
    for (int j = 0; j < 8; ++j)
        if ((sigma_fwd(1 << j, 1) >> (7 - q)) & 1) m |= 1 << j;
    return m;
}
__host__ __device__ constexpr int colmask2(int b) {
    return sigma_fwd(sigma_fwd(1 << b, 1), 2);
}

// ---------- amp-index bit assignment (4 samples/wave, 16 amps/lane, SoA f16x2) ----------
// b7=slot, b6=k2, b1=k1, b0=k0 ; lane bits: b5<->hl0(w=1), b4<->hl2(w=4), b3<->hl3(w=8), b2<->hl1(w=2)
// Gate census (pairmask {C0,60,30,18,0C,06,03,C1}):
//   G0 local(rot16+k4) | G1 DPPxor1+k4 | G2 swz5 | G3 swz12 | G4 swz10
//   G5 DPPxor2+k2      | G6 k3 (pure reg) | G7 local(rot16+k5)
__host__ __device__ constexpr int amp_index(int slot, int k, int hl) {
    return (slot << 7) | (((k >> 2) & 1) << 6) | ((hl & 1) << 5) | (((hl >> 2) & 1) << 4)
         | (((hl >> 3) & 1) << 3) | (((hl >> 1) & 1) << 2) | (((k >> 1) & 1) << 1) | (k & 1);
}
__host__ __device__ constexpr int mask_slot(int M) { return (M >> 7) & 1; }
__host__ __device__ constexpr int mask_k(int M) {
    return (((M >> 6) & 1) << 2) | (((M >> 1) & 1) << 1) | (M & 1);
}
__host__ __device__ constexpr int mask_l(int M) {
    return ((M >> 5) & 1) * 1 + (((M >> 4) & 1)) * 4 + (((M >> 3) & 1)) * 8 + (((M >> 2) & 1)) * 2;
}

typedef _Float16 h2v __attribute__((ext_vector_type(2)));

__device__ __forceinline__ __half2 bc_h2(uint32_t u) { return __builtin_bit_cast(__half2, u); }
__device__ __forceinline__ uint32_t bc_u32(__half2 h) { return __builtin_bit_cast(uint32_t, h); }
__device__ __forceinline__ h2v bc_hv(__half2 h) { return __builtin_bit_cast(h2v, h); }
__device__ __forceinline__ uint32_t rot16(uint32_t u) { return (u >> 16) | (u << 16); }

// lane' = lane ^ XM via BitMode ds_swizzle (XM<16 stays within 16-lane sample group)
template<int XM>
__device__ __forceinline__ uint32_t swzu(uint32_t v) {
    return (uint32_t)__builtin_amdgcn_ds_swizzle((int)v, (XM << 10) | 0x1F);
}
template<int XM>
__device__ __forceinline__ float swzf(float v) {
    return __builtin_bit_cast(float, (uint32_t)__builtin_amdgcn_ds_swizzle(
        (int)__builtin_bit_cast(uint32_t, v), (XM << 10) | 0x1F));
}
// DPP lane permutes (VALU pipe): xor1=0xB1, xor2=0x4E, xor3=0x1B, row_mirror(l^15)=0x140
template<int CTRL>
__device__ __forceinline__ uint32_t dppx(uint32_t v) {
    return (uint32_t)__builtin_amdgcn_update_dpp(0, (int)v, CTRL, 0xF, 0xF, true);
}
template<int CTRL>
__device__ __forceinline__ float dppaddf(float v) {
    const uint32_t p = (uint32_t)__builtin_amdgcn_update_dpp(
        0, (int)__builtin_bit_cast(uint32_t, v), CTRL, 0xF, 0xF, true);
    return v + __builtin_bit_cast(float, p);
}

__device__ __forceinline__ void cmul(float& zr, float& zi,
                                     float xr, float xi, float yr, float yi) {
    const float tr = xr * yr - xi * yi;
    const float ti = xr * yi + xi * yr;
    zr = tr; zi = ti;
}

// packed complex pair {slot0, slot1} and broadcast complex coefficient
struct H2C { __half2 re, im; };
struct YB  { __half2 re, im, imn; };
__device__ __forceinline__ YB mkyb(float r, float i) {
    YB y;
    y.re  = __floats2half2_rn(r, r);
    y.im  = __floats2half2_rn(i, i);
    y.imn = bc_h2(bc_u32(y.im) ^ 0x80008000u);
    return y;
}
__device__ __forceinline__ H2C h2c_mul(H2C x, YB y) {
    H2C z;
    z.re = __hfma2(x.im, y.imn, __hmul2(x.re, y.re));
    z.im = __hfma2(x.im, y.re,  __hmul2(x.re, y.im));
    return z;
}

// ---------- generalized layer-2 gate, SoA packed f16, 16 amps/lane ----------
template<int Q>
__device__ __forceinline__ void gateQ(__half2 re[8], __half2 im[8], int hl,
                                      const uint32_t* __restrict__ cw)
{
    constexpr int M  = pairmask(Q);
    constexpr int RM = rolemask(Q);
    constexpr int mk = mask_k(M);
    constexpr int ml = mask_l(M);
    constexpr int ms = mask_slot(M);
    constexpr int rk = mask_k(RM);
    constexpr int rl = mask_l(RM);

    const uint4    c4v = *(const uint4*)(cw + Q * 8); // {WA, WB0, WC0(-C), WD}
    const uint32_t WDn = cw[Q * 8 + 4];               // {-D,-D}

    const uint32_t pm = (uint32_t)(__popc(hl & rl) & 1) * 0x80008000u;
    const uint32_t Bp = c4v.y ^ pm, Bn = Bp ^ 0x80008000u;
    const uint32_t Cp = c4v.z ^ pm, Cn = Cp ^ 0x80008000u;
    const __half2  Aw = bc_h2(c4v.x);
    const __half2  Dw = bc_h2(c4v.w);
    const __half2  Dn = bc_h2(WDn);

    auto prep = [](uint32_t v) -> uint32_t {
        if constexpr (ms) v = rot16(v);
        if constexpr (ml == 1) v = dppx<0xB1>(v);
        else if constexpr (ml == 2) v = dppx<0x4E>(v);
        else if constexpr (ml == 3) v = dppx<0x1B>(v);
        else if constexpr (ml != 0) v = swzu<ml>(v);
        return v;
    };
    auto upd = [&](int k, uint32_t pr, uint32_t pi) {
        const bool par = (__popc(k & rk) & 1) != 0;   // compile-time after unroll
        const __half2 B1 = bc_h2(par ? Bn : Bp);
        const __half2 B2 = bc_h2(par ? Bp : Bn);
        const __half2 Cc = bc_h2(par ? Cn : Cp);
        __half2 nr = __hmul2(Aw, re[k]);
        nr = __hfma2(B1, im[k], nr);
        nr = __hfma2(Cc, bc_h2(pr), nr);
        nr = __hfma2(Dw, bc_h2(pi), nr);
        __half2 ni = __hmul2(Aw, im[k]);
        ni = __hfma2(B2, re[k], ni);
        ni = __hfma2(Cc, bc_h2(pi), ni);
        ni = __hfma2(Dn, bc_h2(pr), ni);
        re[k] = nr; im[k] = ni;
    };

    if constexpr (mk == 0) {
#pragma unroll
        for (int k = 0; k < 8; ++k) {
            const uint32_t pr = prep(bc_u32(re[k]));
            const uint32_t pi = prep(bc_u32(im[k]));
            upd(k, pr, pi);
        }
    } else {
        constexpr int msb = (mk & 4) ? 4 : ((mk & 2) ? 2 : 1);
#pragma unroll
        for (int k = 0; k < 8; ++k) {
            if ((k & msb) != 0) continue;            // compile-time (unrolled)
            const int k2 = k ^ mk;
            const uint32_t pr_k  = prep(bc_u32(re[k2]));
            const uint32_t pi_k  = prep(bc_u32(im[k2]));
            const uint32_t pr_k2 = prep(bc_u32(re[k]));
            const uint32_t pi_k2 = prep(bc_u32(im[k]));
            upd(k,  pr_k,  pi_k);
            upd(k2, pr_k2, pi_k2);
        }
    }
}

// ---------- single fused kernel: block = 16 samples, 4 samples/wave ----------
__global__ __launch_bounds__(256) void vqe_fused(
    const float* __restrict__ x,       // (B,8)
    const float* __restrict__ weights, // (2,8,3)
    const float* __restrict__ fc_w,    // (8)
    const float* __restrict__ fc_b,    // (1)
    float* __restrict__ out, int B)
{
    __shared__ __align__(16) float    g0[64];        // layer-0 Rot entries (f32)
    __shared__ __align__(16) uint32_t cw[64];        // layer-1 coeff words, 8/gate
    __shared__ __align__(16) float    cols[16 * 36]; // [s][q][4]={ar,ai,br,bi}, stride 36
    __shared__ __align__(16) uint32_t wth2[16 * 12]; // [hl][k] f16x2 {w_s0,w_s1}, stride 12

    const int t = threadIdx.x;

    // --- phase A: shared trig (t<16) + packed weight table (t>=128) ---
    if (t < 8) {
        const float* w3 = weights + t * 3;
        float s, c;   __sincosf(w3[1] * 0.5f, &s, &c);
        float sa, ca; __sincosf(0.5f * (w3[0] + w3[2]), &sa, &ca);
        float sb, cb; __sincosf(0.5f * (w3[0] - w3[2]), &sb, &cb);
        float* g = g0 + t * 8;
        g[0] = c * ca;  g[1] = -c * sa;
        g[2] = -s * cb; g[3] = -s * sb;
        g[4] = s * cb;  g[5] = -s * sb;
        g[6] = c * ca;  g[7] = c * sa;
    } else if (t < 16) {
        const int q = t - 8;
        const float* w3 = weights + (NQ + q) * 3;
        float s, c;   __sincosf(w3[1] * 0.5f, &s, &c);
        float sa, ca; __sincosf(0.5f * (w3[0] + w3[2]), &sa, &ca);
        float sb, cb; __sincosf(0.5f * (w3[0] - w3[2]), &sb, &cb);
        const float A = c * ca, Bc = c * sa, C = s * cb, D = s * sb;
        const float s1 = (rolemask(q) & 0x80) ? -1.f : 1.f;   // slot-bit role sign
        uint32_t* cq = cw + q * 8;
        cq[0] = bc_u32(__floats2half2_rn(A, A));
        cq[1] = bc_u32(__floats2half2_rn(Bc, s1 * Bc));
        cq[2] = bc_u32(__floats2half2_rn(-C, -s1 * C));
        cq[3] = bc_u32(__floats2half2_rn(D, D));
        cq[4] = bc_u32(__floats2half2_rn(-D, -D));
        cq[5] = 0; cq[6] = 0; cq[7] = 0;
    } else if (t >= 128) {
        const int tt = t - 128;                // 0..127 -> [hl 0..15][k 0..7]
        const int whl = tt >> 3, wk = tt & 7;
        float wsl[2];
#pragma unroll
        for (int slot = 0; slot < 2; ++slot) {
            const int s = amp_index(slot, wk, whl);
            int j = 0;
#pragma unroll
            for (int b = 0; b < 8; ++b)
                if ((s >> b) & 1) j ^= colmask2(b);
            float w = 0.f;
#pragma unroll
            for (int q = 0; q < 8; ++q)
                w += ((j >> (7 - q)) & 1) ? -fc_w[q] : fc_w[q];
            wsl[slot] = w;
        }
        wth2[whl * 12 + wk] = bc_u32(__floats2half2_rn(wsl[0], wsl[1]));
    }
    __syncthreads();

    // --- phase B: cooperative per-sample columns (1 sincos per thread, t<128) ---
    if (t < 128) {
        const int s = t >> 3, q = t & 7;
        const int sg = blockIdx.x * 16 + s;
        if (sg < B) {
            const float xv = x[sg * NQ + q];
            float sn, cs; __sincosf(xv * 0.5f, &sn, &cs);
            const float* g = g0 + q * 8;
            float* c = cols + s * 36 + q * 4;
            c[0] = cs * g[0] + sn * g[3];   // a_r
            c[1] = cs * g[1] - sn * g[2];   // a_i
            c[2] = cs * g[4] + sn * g[7];   // b_r
            c[3] = cs * g[5] - sn * g[6];   // b_i
        }
    }
    __syncthreads();

    // --- main: 4 samples/wave, 16 lanes each, 16 amps/lane (8 re + 8 im f16x2) ---
    const int lane = t & 63;
    const int hl   = lane & 15;
    const int sidx = ((t >> 6) << 2) | ((lane >> 4) & 3);   // 0..15
    const int samp = blockIdx.x * 16 + sidx;
    if (samp >= B) return;

    const float* cb = cols + sidx * 36;

    // lane wires 2,3,4,5 <- hl bits 0,2,3,1: selected column halves, f32 chain
    const float2 e2 = *(const float2*)(cb + 2 * 4 + (hl & 1) * 2);
    const float2 e3 = *(const float2*)(cb + 3 * 4 + ((hl >> 2) & 1) * 2);
    const float2 e4 = *(const float2*)(cb + 4 * 4 + ((hl >> 3) & 1) * 2);
    const float2 e5 = *(const float2*)(cb + 5 * 4 + ((hl >> 1) & 1) * 2);
    float cr = e2.x, ci = e2.y;
    cmul(cr, ci, cr, ci, e3.x, e3.y);
    cmul(cr, ci, cr, ci, e4.x, e4.y);
    cmul(cr, ci, cr, ci, e5.x, e5.y);

    // full columns: wire0 (slot), wire1 (k2), wire6 (k1), wire7 (k0)
    const float4 c0 = *(const float4*)(cb + 0 * 4);
    const float4 c1 = *(const float4*)(cb + 1 * 4);
    const float4 c6 = *(const float4*)(cb + 6 * 4);
    const float4 c7 = *(const float4*)(cb + 7 * 4);

    // slot stage: S = {c*a0, c*b0}
    float w0r, w0i, w1r, w1i;
    cmul(w0r, w0i, cr, ci, c0.x, c0.y);
    cmul(w1r, w1i, cr, ci, c0.z, c0.w);
    H2C S{__floats2half2_rn(w0r, w1r), __floats2half2_rn(w0i, w1i)};

    // doubling tree over reg qubits k2(wire1), k1(wire6), k0(wire7); k = k2*4+k1*2+k0
    const YB y1a = mkyb(c1.x, c1.y), y1b = mkyb(c1.z, c1.w);
    const YB y6a = mkyb(c6.x, c6.y), y6b = mkyb(c6.z, c6.w);
    const YB y7a = mkyb(c7.x, c7.y), y7b = mkyb(c7.z, c7.w);

    const H2C A0 = h2c_mul(S, y1a);
    const H2C A1 = h2c_mul(S, y1b);
    H2C Bv[4];
    Bv[0] = h2c_mul(A0, y6a); Bv[1] = h2c_mul(A0, y6b);
    Bv[2] = h2c_mul(A1, y6a); Bv[3] = h2c_mul(A1, y6b);
    __half2 re[8], im[8];
#pragma unroll
    for (int j = 0; j < 4; ++j) {
        const H2C z0 = h2c_mul(Bv[j], y7a);
        const H2C z1 = h2c_mul(Bv[j], y7b);
        re[j * 2 + 0] = z0.re; im[j * 2 + 0] = z0.im;
        re[j * 2 + 1] = z1.re; im[j * 2 + 1] = z1.im;
    }

    // layer-2 Rot gates (CNOT layers folded away; algebra validated rounds 2-9)
    gateQ<0>(re, im, hl, cw);
    gateQ<1>(re, im, hl, cw);
    gateQ<2>(re, im, hl, cw);
    gateQ<3>(re, im, hl, cw);
    gateQ<4>(re, im, hl, cw);
    gateQ<5>(re, im, hl, cw);
    gateQ<6>(re, im, hl, cw);
    gateQ<7>(re, im, hl, cw);

    // readout: acc += w*(re^2 + im^2) via packed mul + v_dot2_f32_f16
    const uint32_t* wrow = wth2 + hl * 12;
    const uint4 wa = *(const uint4*)(wrow + 0);
    const uint4 wb = *(const uint4*)(wrow + 4);
    const uint32_t wkw[8] = {wa.x, wa.y, wa.z, wa.w, wb.x, wb.y, wb.z, wb.w};

    float acc = 0.f;
#pragma unroll
    for (int k = 0; k < 8; ++k) {
        const __half2 W = bc_h2(wkw[k]);
        const __half2 tr_ = __hmul2(re[k], W);
        const __half2 ti_ = __hmul2(im[k], W);
#if defined(__has_builtin) && __has_builtin(__builtin_amdgcn_fdot2)
        acc = __builtin_amdgcn_fdot2(bc_hv(tr_), bc_hv(re[k]), acc, false);
        acc = __builtin_amdgcn_fdot2(bc_hv(ti_), bc_hv(im[k]), acc, false);
#else
        acc += __low2float(tr_) * __low2float(re[k]) + __high2float(tr_) * __high2float(re[k]);
        acc += __low2float(ti_) * __low2float(im[k]) + __high2float(ti_) * __high2float(im[k]);
#endif
    }
    // 16-lane reduce: DPP xor1, xor2, row_mirror(l^15) -> quads {q, q^3}; final xor4 swizzle
    acc = dppaddf<0xB1>(acc);
    acc = dppaddf<0x4E>(acc);
    acc = dppaddf<0x140>(acc);
    acc += swzf<4>(acc);

    if (hl == 0) {
        const float z = acc + fc_b[0];
        out[samp] = 1.0f / (1.0f + __expf(-z));
    }
}

extern "C" void kernel_launch(void* const* d_in, const int* in_sizes, int n_in,
                              void* d_out, int out_size, void* d_ws, size_t ws_size,
                              hipStream_t stream) {
    const float* x       = (const float*)d_in[0];
    const float* weights = (const float*)d_in[1];
    const float* fc_w    = (const float*)d_in[2];
    const float* fc_b    = (const float*)d_in[3];
    float* out = (float*)d_out;
    (void)d_ws; (void)ws_size;

    const int B = in_sizes[0] / NQ;        // 32768
    const int blocks = (B + 15) / 16;      // 16 samples per 256-thread block (4/wave)

    vqe_fused<<<blocks, 256, 0, stream>>>(x, weights, fc_w, fc_b, out, B);
}

// Round 12
// 18.035 us; speedup vs baseline: 1.7190x; 1.0599x over previous
//
#include <hip/hip_runtime.h>
#include <hip/hip_fp16.h>
#include <math.h>

#define NQ 8

// ---------- compile-time GF(2) circuit algebra (validated: rounds 2-11, absmax=0 in f32) ----------
// wire w <-> amp-index bit (7-w). CNOT(c,t): bit_t ^= bit_c.
__host__ __device__ constexpr int cnot_step(int i, int c, int t) {
    return ((i >> (7 - c)) & 1) ? (i ^ (1 << (7 - t))) : i;
}
__host__ __device__ constexpr int sigma_fwd(int i, int r) {
    for (int q = 0; q < 8; ++q) i = cnot_step(i, q, (q + r) & 7);
    return i;
}
__host__ __device__ constexpr int sigma_inv(int i, int r) {
    for (int q = 7; q >= 0; --q) i = cnot_step(i, q, (q + r) & 7);
    return i;
}
__host__ __device__ constexpr int pairmask(int q) { return sigma_inv(1 << (7 - q), 1); }
__host__ __device__ constexpr int rolemask(int q) {
    int m = 0;
    for (int j = 0; j < 8; ++j)
        if ((sigma_fwd(1 << j, 1) >> (7 - q)) & 1) m |= 1 << j;
    return m;
}
__host__ __device__ constexpr int colmask2(int b) {
    return sigma_fwd(sigma_fwd(1 << b, 1), 2);
}

// ---------- amp-index bit assignment (8 samples/wave, 32 amps/lane, SoA f16x2) ----------
// b7=slot, b6=k3, b5=hl0, b4=hl1, b3=hl2, b2=k2, b1=k1, b0=k0
__host__ __device__ constexpr int amp_index(int slot, int k, int hl) {
    return (slot << 7) | (((k >> 3) & 1) << 6) | ((hl & 1) << 5) | (((hl >> 1) & 1) << 4)
         | (((hl >> 2) & 1) << 3) | (((k >> 2) & 1) << 2) | (((k >> 1) & 1) << 1) | (k & 1);
}
__host__ __device__ constexpr int mask_slot(int M) { return (M >> 7) & 1; }
__host__ __device__ constexpr int mask_k(int M) {
    return (((M >> 6) & 1) << 3) | (((M >> 2) & 1) << 2) | (((M >> 1) & 1) << 1) | (M & 1);
}
__host__ __device__ constexpr int mask_l(int M) {
    return ((M >> 5) & 1) | (((M >> 4) & 1) << 1) | (((M >> 3) & 1) << 2);
}

typedef _Float16 h2v __attribute__((ext_vector_type(2)));

__device__ __forceinline__ __half2 bc_h2(uint32_t u) { return __builtin_bit_cast(__half2, u); }
__device__ __forceinline__ uint32_t bc_u32(__half2 h) { return __builtin_bit_cast(uint32_t, h); }
__device__ __forceinline__ h2v bc_hv(__half2 h) { return __builtin_bit_cast(h2v, h); }
__device__ __forceinline__ uint32_t rot16(uint32_t u) { return (u >> 16) | (u << 16); }

// lane' = lane ^ XM via BitMode ds_swizzle (stays within 8-lane sample group for XM<8)
template<int XM>
__device__ __forceinline__ uint32_t swzu(uint32_t v) {
    return (uint32_t)__builtin_amdgcn_ds_swizzle((int)v, (XM << 10) | 0x1F);
}
// lane' = lane ^ {1,3} via quad-perm DPP (VALU, no LDS pipe)
template<int CTRL>
__device__ __forceinline__ uint32_t dppx(uint32_t v) {
    return (uint32_t)__builtin_amdgcn_update_dpp(0, (int)v, CTRL, 0xF, 0xF, true);
}
// reduction add with fused DPP permute: xor1=0xB1, xor2=0x4E, lane^7=row_half_mirror=0x141
template<int CTRL>
__device__ __forceinline__ float dppaddf(float v) {
    const uint32_t p = (uint32_t)__builtin_amdgcn_update_dpp(
        0, (int)__builtin_bit_cast(uint32_t, v), CTRL, 0xF, 0xF, true);
    return v + __builtin_bit_cast(float, p);
}

__device__ __forceinline__ void cmul(float& zr, float& zi,
                                     float xr, float xi, float yr, float yi) {
    const float tr = xr * yr - xi * yi;
    const float ti = xr * yi + xi * yr;
    zr = tr; zi = ti;
}

// packed complex pair {slot0, slot1} and broadcast complex coefficient
struct H2C { __half2 re, im; };
struct YB  { __half2 re, im, imn; };
__device__ __forceinline__ YB mkyb(float r, float i) {
    YB y;
    y.re  = __floats2half2_rn(r, r);
    y.im  = __floats2half2_rn(i, i);
    y.imn = bc_h2(bc_u32(y.im) ^ 0x80008000u);
    return y;
}
__device__ __forceinline__ H2C h2c_mul(H2C x, YB y) {
    H2C z;
    z.re = __hfma2(x.im, y.imn, __hmul2(x.re, y.re));
    z.im = __hfma2(x.im, y.re,  __hmul2(x.re, y.im));
    return z;
}

// ---------- generalized layer-2 gate, SoA packed f16, 32 amps/lane ----------
// Coefficients arrive as REGISTER scalars (hoisted batch load) — no per-gate LDS stall.
template<int Q>
__device__ __forceinline__ void gateQ(__half2 re[16], __half2 im[16], int hl,
                                      uint32_t wAu, uint32_t wBu, uint32_t wCu,
                                      uint32_t wDu, uint32_t wDnu)
{
    constexpr int M  = pairmask(Q);
    constexpr int RM = rolemask(Q);
    constexpr int mk = mask_k(M);
    constexpr int ml = mask_l(M);
    constexpr int ms = mask_slot(M);
    constexpr int rk = mask_k(RM);
    constexpr int rl = mask_l(RM);

    const uint32_t pm = (uint32_t)(__popc(hl & rl) & 1) * 0x80008000u;
    const uint32_t Bp = wBu ^ pm, Bn = Bp ^ 0x80008000u;
    const uint32_t Cp = wCu ^ pm, Cn = Cp ^ 0x80008000u;
    const __half2  Aw = bc_h2(wAu);
    const __half2  Dw = bc_h2(wDu);
    const __half2  Dn = bc_h2(wDnu);

    auto prep = [](uint32_t v) -> uint32_t {
        if constexpr (ms) v = rot16(v);
        if constexpr (ml == 1) v = dppx<0xB1>(v);
        else if constexpr (ml == 3) v = dppx<0x1B>(v);
        else if constexpr (ml != 0) v = swzu<ml>(v);
        return v;
    };
    auto upd = [&](int k, uint32_t pr, uint32_t pi) {
        const bool par = (__popc(k & rk) & 1) != 0;   // compile-time after unroll
        const __half2 B1 = bc_h2(par ? Bn : Bp);
        const __half2 B2 = bc_h2(par ? Bp : Bn);
        const __half2 Cc = bc_h2(par ? Cn : Cp);
        __half2 nr = __hmul2(Aw, re[k]);
        nr = __hfma2(B1, im[k], nr);
        nr = __hfma2(Cc, bc_h2(pr), nr);
        nr = __hfma2(Dw, bc_h2(pi), nr);
        __half2 ni = __hmul2(Aw, im[k]);
        ni = __hfma2(B2, re[k], ni);
        ni = __hfma2(Cc, bc_h2(pi), ni);
        ni = __hfma2(Dn, bc_h2(pr), ni);
        re[k] = nr; im[k] = ni;
    };

    if constexpr (mk == 0) {
#pragma unroll
        for (int k = 0; k < 16; ++k) {
            const uint32_t pr = prep(bc_u32(re[k]));
            const uint32_t pi = prep(bc_u32(im[k]));
            upd(k, pr, pi);
        }
    } else {
        constexpr int msb = (mk & 8) ? 8 : ((mk & 4) ? 4 : ((mk & 2) ? 2 : 1));
#pragma unroll
        for (int k = 0; k < 16; ++k) {
            if ((k & msb) != 0) continue;            // compile-time (unrolled)
            const int k2 = k ^ mk;
            const uint32_t pr_k  = prep(bc_u32(re[k2]));
            const uint32_t pi_k  = prep(bc_u32(im[k2]));
            const uint32_t pr_k2 = prep(bc_u32(re[k]));
            const uint32_t pi_k2 = prep(bc_u32(im[k]));
            upd(k,  pr_k,  pi_k);
            upd(k2, pr_k2, pi_k2);
        }
    }
}

// ---------- single fused kernel: block = 32 samples, wave-local phase B ----------
__global__ __launch_bounds__(256) void vqe_fused(
    const float* __restrict__ x,       // (B,8)
    const float* __restrict__ weights, // (2,8,3)
    const float* __restrict__ fc_w,    // (8)
    const float* __restrict__ fc_b,    // (1)
    float* __restrict__ out, int B)
{
    __shared__ __align__(16) float    g0[64];        // layer-0 Rot entries (f32)
    __shared__ __align__(16) uint32_t cw[64];        // layer-1 coeff words, 8/gate
    __shared__ __align__(16) float    cols[32 * 36]; // [s][q][4]={ar,ai,br,bi}, stride 36
    __shared__ __align__(16) uint32_t wth2[8 * 20];  // [hl][k] f16x2 {w_s0,w_s1}, stride 20

    const int t = threadIdx.x;

    // --- phase A: shared trig (t<16) + packed weight table (t>=128) ---
    if (t < 8) {
        const float* w3 = weights + t * 3;
        float s, c;   __sincosf(w3[1] * 0.5f, &s, &c);
        float sa, ca; __sincosf(0.5f * (w3[0] + w3[2]), &sa, &ca);
        float sb, cb; __sincosf(0.5f * (w3[0] - w3[2]), &sb, &cb);
        float* g = g0 + t * 8;
        g[0] = c * ca;  g[1] = -c * sa;
        g[2] = -s * cb; g[3] = -s * sb;
        g[4] = s * cb;  g[5] = -s * sb;
        g[6] = c * ca;  g[7] = c * sa;
    } else if (t < 16) {
        const int q = t - 8;
        const float* w3 = weights + (NQ + q) * 3;
        float s, c;   __sincosf(w3[1] * 0.5f, &s, &c);
        float sa, ca; __sincosf(0.5f * (w3[0] + w3[2]), &sa, &ca);
        float sb, cb; __sincosf(0.5f * (w3[0] - w3[2]), &sb, &cb);
        const float A = c * ca, Bc = c * sa, C = s * cb, D = s * sb;
        const float s1 = (rolemask(q) & 0x80) ? -1.f : 1.f;   // slot-bit role sign
        uint32_t* cq = cw + q * 8;
        cq[0] = bc_u32(__floats2half2_rn(A, A));
        cq[1] = bc_u32(__floats2half2_rn(Bc, s1 * Bc));
        cq[2] = bc_u32(__floats2half2_rn(-C, -s1 * C));
        cq[3] = bc_u32(__floats2half2_rn(D, D));
        cq[4] = bc_u32(__floats2half2_rn(-D, -D));
        cq[5] = 0; cq[6] = 0; cq[7] = 0;
    } else if (t >= 128) {
        const int tt = t - 128;                // 0..127
        const int whl = tt >> 4, wk = tt & 15;
        float wsl[2];
#pragma unroll
        for (int slot = 0; slot < 2; ++slot) {
            const int s = amp_index(slot, wk, whl);
            int j = 0;
#pragma unroll
            for (int b = 0; b < 8; ++b)
                if ((s >> b) & 1) j ^= colmask2(b);
            float w = 0.f;
#pragma unroll
            for (int q = 0; q < 8; ++q)
                w += ((j >> (7 - q)) & 1) ? -fc_w[q] : fc_w[q];
            wsl[slot] = w;
        }
        wth2[whl * 20 + wk] = bc_u32(__floats2half2_rn(wsl[0], wsl[1]));
    }
    __syncthreads();   // barrier #1: g0/cw/wth2 visible block-wide

    // --- phase B: WAVE-LOCAL per-sample columns ---
    // lane l of wave w computes (sample (l>>3), qubit l&7) of the wave's own 8 samples,
    // exactly the rows this wave reads in the main path -> no block barrier needed.
    {
        const int lane6 = t & 63;
        const int s = ((t >> 6) << 3) | (lane6 >> 3);   // 0..31, wave-local
        const int q = lane6 & 7;
        const int sg = blockIdx.x * 32 + s;
        if (sg < B) {
            const float xv = x[sg * NQ + q];   // global idx = blockIdx*256 + t : coalesced
            float sn, cs; __sincosf(xv * 0.5f, &sn, &cs);
            const float* g = g0 + q * 8;
            float* c = cols + s * 36 + q * 4;
            c[0] = cs * g[0] + sn * g[3];   // a_r
            c[1] = cs * g[1] - sn * g[2];   // a_i
            c[2] = cs * g[4] + sn * g[7];   // b_r
            c[3] = cs * g[5] - sn * g[6];   // b_i
        }
    }
    // wave-local visibility: drain this wave's LDS writes; fence compiler motion (rule #18)
    asm volatile("s_waitcnt lgkmcnt(0)" ::: "memory");
    __builtin_amdgcn_sched_barrier(0);

    // --- main: 8 samples/wave, 8 lanes each, 32 amps/lane (16 re + 16 im f16x2) ---
    const int lane = t & 63;
    const int hl   = lane & 7;
    const int sidx = ((t >> 6) << 3) | ((lane >> 3) & 7);   // 0..31 (matches phase B)
    const int samp = blockIdx.x * 32 + sidx;
    if (samp >= B) return;

    const float* cb = cols + sidx * 36;

    // issue all cols reads ...
    const float2 e2 = *(const float2*)(cb + 2 * 4 + (hl & 1) * 2);
    const float2 e3 = *(const float2*)(cb + 3 * 4 + ((hl >> 1) & 1) * 2);
    const float2 e4 = *(const float2*)(cb + 4 * 4 + ((hl >> 2) & 1) * 2);
    const float4 c0 = *(const float4*)(cb + 0 * 4);
    const float4 c1 = *(const float4*)(cb + 1 * 4);
    const float4 c5 = *(const float4*)(cb + 5 * 4);
    const float4 c6 = *(const float4*)(cb + 6 * 4);
    const float4 c7 = *(const float4*)(cb + 7 * 4);

    // ... and ALL gate coefficients as one batched burst into registers (constant
    // indices after unroll -> VGPRs, rule #20). Latency hides under embedding VALU.
    uint32_t cc[40];
#pragma unroll
    for (int qg = 0; qg < 8; ++qg) {
        const uint4 v4 = *(const uint4*)(cw + qg * 8);
        cc[qg * 5 + 0] = v4.x;
        cc[qg * 5 + 1] = v4.y;
        cc[qg * 5 + 2] = v4.z;
        cc[qg * 5 + 3] = v4.w;
        cc[qg * 5 + 4] = cw[qg * 8 + 4];
    }

    // lane wires 2,3,4 <- hl bits 0,1,2: selected column halves, f32 chain
    float cr = e2.x, ci = e2.y;
    cmul(cr, ci, cr, ci, e3.x, e3.y);
    cmul(cr, ci, cr, ci, e4.x, e4.y);

    // slot stage: S = {c*a0, c*b0}
    float w0r, w0i, w1r, w1i;
    cmul(w0r, w0i, cr, ci, c0.x, c0.y);
    cmul(w1r, w1i, cr, ci, c0.z, c0.w);
    H2C S{__floats2half2_rn(w0r, w1r), __floats2half2_rn(w0i, w1i)};

    // doubling tree over reg qubits k3(wire1), k2(wire5), k1(wire6), k0(wire7)
    const YB y1a = mkyb(c1.x, c1.y), y1b = mkyb(c1.z, c1.w);
    const YB y5a = mkyb(c5.x, c5.y), y5b = mkyb(c5.z, c5.w);
    const YB y6a = mkyb(c6.x, c6.y), y6b = mkyb(c6.z, c6.w);
    const YB y7a = mkyb(c7.x, c7.y), y7b = mkyb(c7.z, c7.w);

    const H2C A0 = h2c_mul(S, y1a);
    const H2C A1 = h2c_mul(S, y1b);
    H2C Bv[4];
    Bv[0] = h2c_mul(A0, y5a); Bv[1] = h2c_mul(A0, y5b);
    Bv[2] = h2c_mul(A1, y5a); Bv[3] = h2c_mul(A1, y5b);
    H2C Cv[8];
#pragma unroll
    for (int j = 0; j < 4; ++j) {
        Cv[j * 2 + 0] = h2c_mul(Bv[j], y6a);
        Cv[j * 2 + 1] = h2c_mul(Bv[j], y6b);
    }
    __half2 re[16], im[16];
#pragma unroll
    for (int j = 0; j < 8; ++j) {
        const H2C z0 = h2c_mul(Cv[j], y7a);
        const H2C z1 = h2c_mul(Cv[j], y7b);
        re[j * 2 + 0] = z0.re; im[j * 2 + 0] = z0.im;
        re[j * 2 + 1] = z1.re; im[j * 2 + 1] = z1.im;
    }

    // layer-2 Rot gates (CNOT layers folded away; algebra validated rounds 2-11)
    gateQ<0>(re, im, hl, cc[ 0], cc[ 1], cc[ 2], cc[ 3], cc[ 4]);
    gateQ<1>(re, im, hl, cc[ 5], cc[ 6], cc[ 7], cc[ 8], cc[ 9]);
    gateQ<2>(re, im, hl, cc[10], cc[11], cc[12], cc[13], cc[14]);
    gateQ<3>(re, im, hl, cc[15], cc[16], cc[17], cc[18], cc[19]);
    gateQ<4>(re, im, hl, cc[20], cc[21], cc[22], cc[23], cc[24]);
    gateQ<5>(re, im, hl, cc[25], cc[26], cc[27], cc[28], cc[29]);
    gateQ<6>(re, im, hl, cc[30], cc[31], cc[32], cc[33], cc[34]);
    gateQ<7>(re, im, hl, cc[35], cc[36], cc[37], cc[38], cc[39]);

    // readout: acc += w*(re^2 + im^2) via packed mul + v_dot2_f32_f16
    const uint32_t* wrow = wth2 + hl * 20;
    const uint4 wa = *(const uint4*)(wrow + 0);
    const uint4 wb = *(const uint4*)(wrow + 4);
    const uint4 wc = *(const uint4*)(wrow + 8);
    const uint4 wd = *(const uint4*)(wrow + 12);
    const uint32_t wkw[16] = {wa.x, wa.y, wa.z, wa.w, wb.x, wb.y, wb.z, wb.w,
                              wc.x, wc.y, wc.z, wc.w, wd.x, wd.y, wd.z, wd.w};

    float acc = 0.f;
#pragma unroll
    for (int k = 0; k < 16; ++k) {
        const __half2 W = bc_h2(wkw[k]);
        const __half2 tr_ = __hmul2(re[k], W);
        const __half2 ti_ = __hmul2(im[k], W);
#if defined(__has_builtin) && __has_builtin(__builtin_amdgcn_fdot2)
        acc = __builtin_amdgcn_fdot2(bc_hv(tr_), bc_hv(re[k]), acc, false);
        acc = __builtin_amdgcn_fdot2(bc_hv(ti_), bc_hv(im[k]), acc, false);
#else
        acc += __low2float(tr_) * __low2float(re[k]) + __high2float(tr_) * __high2float(re[k]);
        acc += __low2float(ti_) * __low2float(im[k]) + __high2float(ti_) * __high2float(im[k]);
#endif
    }
    // 8-lane reduce: DPP xor1, xor2, lane^7 (row_half_mirror)
    acc = dppaddf<0xB1>(acc);
    acc = dppaddf<0x4E>(acc);
    acc = dppaddf<0x141>(acc);

    if (hl == 0) {
        const float z = acc + fc_b[0];
        out[samp] = 1.0f / (1.0f + __expf(-z));
    }
}

extern "C" void kernel_launch(void* const* d_in, const int* in_sizes, int n_in,
                              void* d_out, int out_size, void* d_ws, size_t ws_size,
                              hipStream_t stream) {
    const float* x       = (const float*)d_in[0];
    const float* weights = (const float*)d_in[1];
    const float* fc_w    = (const float*)d_in[2];
    const float* fc_b    = (const float*)d_in[3];
    float* out = (float*)d_out;
    (void)d_ws; (void)ws_size;

    const int B = in_sizes[0] / NQ;        // 32768
    const int blocks = (B + 31) / 32;      // 32 samples per 256-thread block

    vqe_fused<<<blocks, 256, 0, stream>>>(x, weights, fc_w, fc_b, out, B);
}